// Round 7
// baseline (144.520 us; speedup 1.0000x reference)
//
#include <hip/hip_runtime.h>
#include <math.h>

// ---------------------------------------------------------------------------
// Difflogic network, collapsed form, fully fused single kernel:
//   per neuron: out = c0 + c1*p + c2*q + c3*p*q,  p = A·x, q = B·x
//   A,B = softmax(sel), (c0..c3) = softmax(gate_logits) · gate-coef table
//
// R6 -> R7: back to R5's winning body (direct contiguous dwordx4 x-loads,
// straight-line math, float4 stores) but FUSED: every wave redundantly
// computes all 45 coefficient tasks (one per lane) into a shared LDS table.
// All waves write identical bytes -> benign race -> NO __syncthreads anywhere;
// each wave only waits on its own LDS writes (lgkmcnt), which the compiler
// inserts automatically via the memory dependence. This deletes the coeff
// kernel launch + inter-kernel bubble (~5us) that R5 paid.
// Two light compiler fences bound coefficient-load hoisting (R3's spill
// lesson) without R4's 15-way serialization.
//
// scf layout (floats):
//   A1:   0 (72)   B1:  72 (72)   C1: 144 (32)
//   A2: 176 (32)   B2: 208 (32)   C2: 240 (16)
//   A3: 256 ( 8)   B3: 264 ( 8)   C3: 272 ( 8)
//   A4: 280 ( 2)   B4: 282 ( 2)   C4: 284 ( 4)   total 288 floats = 1152 B
// ---------------------------------------------------------------------------

#define THREADS 256
#define SPT 4                          // consecutive samples per thread
#define B_PER_BLOCK (THREADS * SPT)

template <int D>
__device__ __forceinline__ void softmax_row(const float* __restrict__ src,
                                            float* __restrict__ dst) {
    float e[D];
    float m = src[0];
    #pragma unroll
    for (int i = 1; i < D; ++i) m = fmaxf(m, src[i]);
    float s = 0.f;
    #pragma unroll
    for (int i = 0; i < D; ++i) { e[i] = __expf(src[i] - m); s += e[i]; }
    float inv = 1.f / s;
    #pragma unroll
    for (int i = 0; i < D; ++i) dst[i] = e[i] * inv;
}

__device__ __forceinline__ void gate_fold(const float* __restrict__ g,
                                          float* __restrict__ C) {
    const float k0[16]  = {0,0,0,0, 0,0,0,0, 1, 1, 1, 1, 1, 1, 1, 1};
    const float kp[16]  = {0,0,1,1, 0,0,1,1,-1,-1, 0, 0,-1,-1, 0, 0};
    const float kq[16]  = {0,0,0,0, 1,1,1,1,-1,-1,-1,-1, 0, 0, 0, 0};
    const float kpq[16] = {0,1,-1,0,-1,0,-2,-1, 1, 2, 0, 1, 0, 1,-1, 0};
    float w[16];
    float m = g[0];
    #pragma unroll
    for (int i = 1; i < 16; ++i) m = fmaxf(m, g[i]);
    float s = 0.f;
    #pragma unroll
    for (int i = 0; i < 16; ++i) { w[i] = __expf(g[i] - m); s += w[i]; }
    float inv = 1.f / s;
    float c0 = 0, c1 = 0, c2 = 0, c3 = 0;
    #pragma unroll
    for (int i = 0; i < 16; ++i) {
        float wi = w[i] * inv;
        c0 = fmaf(wi, k0[i], c0); c1 = fmaf(wi, kp[i], c1);
        c2 = fmaf(wi, kq[i], c2); c3 = fmaf(wi, kpq[i], c3);
    }
    C[0] = c0; C[1] = c1; C[2] = c2; C[3] = c3;
}

__global__ __launch_bounds__(THREADS, 3) void net_kernel(
        const float* __restrict__ x,
        const float* __restrict__ sa1, const float* __restrict__ sb1, const float* __restrict__ g1,
        const float* __restrict__ sa2, const float* __restrict__ sb2, const float* __restrict__ g2,
        const float* __restrict__ sa3, const float* __restrict__ sb3, const float* __restrict__ g3,
        const float* __restrict__ sa4, const float* __restrict__ sb4, const float* __restrict__ g4,
        float* __restrict__ out, int nB) {
    __shared__ float scf[288];

    const int t    = threadIdx.x;
    const int lane = t & 63;

    // ---- every wave: redundantly compute all 45 coefficient tasks ----
    // All waves write IDENTICAL values -> benign race, no barrier needed.
    // Each wave's own ds_writes are waited on (lgkmcnt) before its reads.
    if (lane < 15) {                       // softmax(sel_a) rows
        int r = lane;
        if      (r < 8)  softmax_row<9>(sa1 + r * 9,        scf + r * 9);
        else if (r < 12) softmax_row<8>(sa2 + (r - 8) * 8,  scf + 176 + (r - 8) * 8);
        else if (r < 14) softmax_row<4>(sa3 + (r - 12) * 4, scf + 256 + (r - 12) * 4);
        else             softmax_row<2>(sa4,                scf + 280);
    } else if (lane >= 16 && lane < 31) {  // softmax(sel_b) rows
        int r = lane - 16;
        if      (r < 8)  softmax_row<9>(sb1 + r * 9,        scf + 72 + r * 9);
        else if (r < 12) softmax_row<8>(sb2 + (r - 8) * 8,  scf + 208 + (r - 8) * 8);
        else if (r < 14) softmax_row<4>(sb3 + (r - 12) * 4, scf + 264 + (r - 12) * 4);
        else             softmax_row<2>(sb4,                scf + 282);
    } else if (lane >= 32 && lane < 47) {  // gate-logit folds
        int r = lane - 32;
        if      (r < 8)  gate_fold(g1 + r * 16,        scf + 144 + r * 4);
        else if (r < 12) gate_fold(g2 + (r - 8) * 16,  scf + 240 + (r - 8) * 4);
        else if (r < 14) gate_fold(g3 + (r - 12) * 16, scf + 272 + (r - 12) * 4);
        else             gate_fold(g4,                 scf + 284);
    }

    // ---- load 4 consecutive samples = 36 contiguous floats = 9 dwordx4 ----
    const int T  = blockIdx.x * THREADS + t;   // sample-group id
    const int b0 = T * SPT;
    if (b0 >= nB) return;

    float v[SPT][9];
    if (b0 + SPT <= nB) {
        const float4* __restrict__ x4 = (const float4*)x;
        float4 r[9];
        #pragma unroll
        for (int k = 0; k < 9; ++k) r[k] = x4[(long)T * 9 + k];
        const float* rf = (const float*)r;
        #pragma unroll
        for (int s = 0; s < SPT; ++s)
            #pragma unroll
            for (int i = 0; i < 9; ++i) v[s][i] = rf[s * 9 + i];
    } else {
        #pragma unroll
        for (int s = 0; s < SPT; ++s)
            #pragma unroll
            for (int i = 0; i < 9; ++i) {
                int b = b0 + s;
                v[s][i] = (b < nB) ? x[(long)b * 9 + i] : 0.f;
            }
    }

    // ---- Layer 1: 9 -> 8 (two 4-neuron chunks; fence bounds hoisting) ----
    float h1[SPT][8];
    #pragma unroll
    for (int jc = 0; jc < 2; ++jc) {
        #pragma unroll
        for (int jj = 0; jj < 4; ++jj) {
            const int j = jc * 4 + jj;
            #pragma unroll
            for (int s = 0; s < SPT; ++s) {
                float p = 0.f, q = 0.f;
                #pragma unroll
                for (int i = 0; i < 9; ++i) {
                    p = fmaf(v[s][i], scf[     j * 9 + i], p);
                    q = fmaf(v[s][i], scf[72 + j * 9 + i], q);
                }
                h1[s][j] = fmaf(scf[144 + j*4 + 3], p * q,
                           fmaf(scf[144 + j*4 + 2], q,
                           fmaf(scf[144 + j*4 + 1], p, scf[144 + j*4 + 0])));
            }
        }
        asm volatile("" ::: "memory");     // cap live coefficient set
    }
    // ---- Layer 2: 8 -> 4 ----
    float h2[SPT][4];
    #pragma unroll
    for (int j = 0; j < 4; ++j) {
        #pragma unroll
        for (int s = 0; s < SPT; ++s) {
            float p = 0.f, q = 0.f;
            #pragma unroll
            for (int i = 0; i < 8; ++i) {
                p = fmaf(h1[s][i], scf[176 + j * 8 + i], p);
                q = fmaf(h1[s][i], scf[208 + j * 8 + i], q);
            }
            h2[s][j] = fmaf(scf[240 + j*4 + 3], p * q,
                       fmaf(scf[240 + j*4 + 2], q,
                       fmaf(scf[240 + j*4 + 1], p, scf[240 + j*4 + 0])));
        }
    }
    // ---- Layer 3: 4 -> 2 ----
    float h3[SPT][2];
    #pragma unroll
    for (int j = 0; j < 2; ++j) {
        #pragma unroll
        for (int s = 0; s < SPT; ++s) {
            float p = 0.f, q = 0.f;
            #pragma unroll
            for (int i = 0; i < 4; ++i) {
                p = fmaf(h2[s][i], scf[256 + j * 4 + i], p);
                q = fmaf(h2[s][i], scf[264 + j * 4 + i], q);
            }
            h3[s][j] = fmaf(scf[272 + j*4 + 3], p * q,
                       fmaf(scf[272 + j*4 + 2], q,
                       fmaf(scf[272 + j*4 + 1], p, scf[272 + j*4 + 0])));
        }
    }
    // ---- Layer 4: 2 -> 1, one float4 store per thread ----
    float o[SPT];
    #pragma unroll
    for (int s = 0; s < SPT; ++s) {
        float p = fmaf(h3[s][0], scf[280], h3[s][1] * scf[281]);
        float q = fmaf(h3[s][0], scf[282], h3[s][1] * scf[283]);
        o[s] = fmaf(scf[287], p * q,
               fmaf(scf[286], q,
               fmaf(scf[285], p, scf[284])));
    }
    if (b0 + SPT <= nB) {
        float4* __restrict__ out4 = (float4*)out;
        float4 w; w.x = o[0]; w.y = o[1]; w.z = o[2]; w.w = o[3];
        out4[T] = w;
    } else {
        #pragma unroll
        for (int s = 0; s < SPT; ++s)
            if (b0 + s < nB) out[b0 + s] = o[s];
    }
}

extern "C" void kernel_launch(void* const* d_in, const int* in_sizes, int n_in,
                              void* d_out, int out_size, void* d_ws, size_t ws_size,
                              hipStream_t stream) {
    const float* x   = (const float*)d_in[0];
    const float* sa1 = (const float*)d_in[1];
    const float* sb1 = (const float*)d_in[2];
    const float* g1  = (const float*)d_in[3];
    const float* sa2 = (const float*)d_in[4];
    const float* sb2 = (const float*)d_in[5];
    const float* g2  = (const float*)d_in[6];
    const float* sa3 = (const float*)d_in[7];
    const float* sb3 = (const float*)d_in[8];
    const float* g3  = (const float*)d_in[9];
    const float* sa4 = (const float*)d_in[10];
    const float* sb4 = (const float*)d_in[11];
    const float* g4  = (const float*)d_in[12];
    const int nB = in_sizes[0] / 9;

    const int grid = (nB + B_PER_BLOCK - 1) / B_PER_BLOCK;
    net_kernel<<<grid, THREADS, 0, stream>>>(
        x, sa1, sb1, g1, sa2, sb2, g2, sa3, sb3, g3, sa4, sb4, g4,
        (float*)d_out, nB);
}

// Round 8
// 107.490 us; speedup vs baseline: 1.3445x; 1.3445x over previous
//
#include <hip/hip_runtime.h>
#include <math.h>

// ---------------------------------------------------------------------------
// Difflogic network, collapsed form:
//   per neuron: out = c0 + c1*p + c2*q + c3*p*q,  p = A·x, q = B·x
//   A,B = softmax(sel), (c0..c3) = softmax(gate_logits) · gate-coef table
//
// R7 -> R8: REVERT to the R5 two-kernel structure (best: 107.6us).
// R7's in-kernel coefficient derivation spilled its private arrays to
// scratch under divergent branches -> 77MB of HBM writes (WRITE_SIZE
// counter), 1024x redundant work. Lesson: keep the irregular softmax code
// in its own tiny kernel where arrays promote to registers cleanly.
// Changes vs R5: parallel 45-lane coeff kernel (R6's, one task/lane) and
// __launch_bounds__(256,4) on net_kernel (body needs ~100 VGPR < 128 cap)
// -> 16 waves/CU for latency hiding.
//
// ws layout (floats):
//   A1:   0 (72)   B1:  72 (72)   C1: 144 (32)
//   A2: 176 (32)   B2: 208 (32)   C2: 240 (16)
//   A3: 256 ( 8)   B3: 264 ( 8)   C3: 272 ( 8)
//   A4: 280 ( 2)   B4: 282 ( 2)   C4: 284 ( 4)   total 288 floats = 1152 B
// ---------------------------------------------------------------------------

#define THREADS 256
#define SPT 4                          // consecutive samples per thread
#define B_PER_BLOCK (THREADS * SPT)

template <int D>
__device__ __forceinline__ void softmax_row(const float* __restrict__ src,
                                            float* __restrict__ dst) {
    float e[D];
    float m = src[0];
    #pragma unroll
    for (int i = 1; i < D; ++i) m = fmaxf(m, src[i]);
    float s = 0.f;
    #pragma unroll
    for (int i = 0; i < D; ++i) { e[i] = __expf(src[i] - m); s += e[i]; }
    float inv = 1.f / s;
    #pragma unroll
    for (int i = 0; i < D; ++i) dst[i] = e[i] * inv;
}

__device__ __forceinline__ void gate_fold(const float* __restrict__ g,
                                          float* __restrict__ C) {
    const float k0[16]  = {0,0,0,0, 0,0,0,0, 1, 1, 1, 1, 1, 1, 1, 1};
    const float kp[16]  = {0,0,1,1, 0,0,1,1,-1,-1, 0, 0,-1,-1, 0, 0};
    const float kq[16]  = {0,0,0,0, 1,1,1,1,-1,-1,-1,-1, 0, 0, 0, 0};
    const float kpq[16] = {0,1,-1,0,-1,0,-2,-1, 1, 2, 0, 1, 0, 1,-1, 0};
    float w[16];
    float m = g[0];
    #pragma unroll
    for (int i = 1; i < 16; ++i) m = fmaxf(m, g[i]);
    float s = 0.f;
    #pragma unroll
    for (int i = 0; i < 16; ++i) { w[i] = __expf(g[i] - m); s += w[i]; }
    float inv = 1.f / s;
    float c0 = 0, c1 = 0, c2 = 0, c3 = 0;
    #pragma unroll
    for (int i = 0; i < 16; ++i) {
        float wi = w[i] * inv;
        c0 = fmaf(wi, k0[i], c0); c1 = fmaf(wi, kp[i], c1);
        c2 = fmaf(wi, kq[i], c2); c3 = fmaf(wi, kpq[i], c3);
    }
    C[0] = c0; C[1] = c1; C[2] = c2; C[3] = c3;
}

__global__ void coeff_kernel(const float* __restrict__ sa1, const float* __restrict__ sb1, const float* __restrict__ g1,
                             const float* __restrict__ sa2, const float* __restrict__ sb2, const float* __restrict__ g2,
                             const float* __restrict__ sa3, const float* __restrict__ sb3, const float* __restrict__ g3,
                             const float* __restrict__ sa4, const float* __restrict__ sb4, const float* __restrict__ g4,
                             float* __restrict__ cf) {
    const int t = threadIdx.x;
    if (t < 15) {                 // softmax of sel_a rows
        int r = t;
        if      (r < 8)  softmax_row<9>(sa1 + r * 9,        cf + r * 9);
        else if (r < 12) softmax_row<8>(sa2 + (r - 8) * 8,  cf + 176 + (r - 8) * 8);
        else if (r < 14) softmax_row<4>(sa3 + (r - 12) * 4, cf + 256 + (r - 12) * 4);
        else             softmax_row<2>(sa4,                cf + 280);
    } else if (t >= 16 && t < 31) {   // softmax of sel_b rows
        int r = t - 16;
        if      (r < 8)  softmax_row<9>(sb1 + r * 9,        cf + 72 + r * 9);
        else if (r < 12) softmax_row<8>(sb2 + (r - 8) * 8,  cf + 208 + (r - 8) * 8);
        else if (r < 14) softmax_row<4>(sb3 + (r - 12) * 4, cf + 264 + (r - 12) * 4);
        else             softmax_row<2>(sb4,                cf + 282);
    } else if (t >= 32 && t < 47) {   // gate-logit folds
        int r = t - 32;
        if      (r < 8)  gate_fold(g1 + r * 16,        cf + 144 + r * 4);
        else if (r < 12) gate_fold(g2 + (r - 8) * 16,  cf + 240 + (r - 8) * 4);
        else if (r < 14) gate_fold(g3 + (r - 12) * 16, cf + 272 + (r - 12) * 4);
        else             gate_fold(g4,                 cf + 284);
    }
}

__global__ __launch_bounds__(THREADS, 4) void net_kernel(
        const float* __restrict__ x, const float* __restrict__ cf,
        float* __restrict__ out, int nB) {
    const int T  = blockIdx.x * THREADS + threadIdx.x;  // sample-group id
    const int b0 = T * SPT;
    if (b0 >= nB) return;

    // ---- load 4 consecutive samples = 36 contiguous floats = 9 dwordx4 ----
    float v[SPT][9];
    if (b0 + SPT <= nB) {
        const float4* __restrict__ x4 = (const float4*)x;
        float4 r[9];
        #pragma unroll
        for (int k = 0; k < 9; ++k) r[k] = x4[(long)T * 9 + k];
        const float* rf = (const float*)r;   // constant-index after unroll -> VGPRs
        #pragma unroll
        for (int s = 0; s < SPT; ++s)
            #pragma unroll
            for (int i = 0; i < 9; ++i) v[s][i] = rf[s * 9 + i];
    } else {
        #pragma unroll
        for (int s = 0; s < SPT; ++s)
            #pragma unroll
            for (int i = 0; i < 9; ++i) {
                int b = b0 + s;
                v[s][i] = (b < nB) ? x[(long)b * 9 + i] : 0.f;
            }
    }

    // ---- Layer 1: 9 -> 8. cf[] = uniform pointer + constant offsets
    //      -> scalar loads; SGPR operands feed v_fma directly. ----
    float h1[SPT][8];
    #pragma unroll
    for (int j = 0; j < 8; ++j) {
        #pragma unroll
        for (int s = 0; s < SPT; ++s) {
            float p = 0.f, q = 0.f;
            #pragma unroll
            for (int i = 0; i < 9; ++i) {
                p = fmaf(v[s][i], cf[     j * 9 + i], p);
                q = fmaf(v[s][i], cf[72 + j * 9 + i], q);
            }
            h1[s][j] = fmaf(cf[144 + j*4 + 3], p * q,
                       fmaf(cf[144 + j*4 + 2], q,
                       fmaf(cf[144 + j*4 + 1], p, cf[144 + j*4 + 0])));
        }
    }
    // ---- Layer 2: 8 -> 4 ----
    float h2[SPT][4];
    #pragma unroll
    for (int j = 0; j < 4; ++j) {
        #pragma unroll
        for (int s = 0; s < SPT; ++s) {
            float p = 0.f, q = 0.f;
            #pragma unroll
            for (int i = 0; i < 8; ++i) {
                p = fmaf(h1[s][i], cf[176 + j * 8 + i], p);
                q = fmaf(h1[s][i], cf[208 + j * 8 + i], q);
            }
            h2[s][j] = fmaf(cf[240 + j*4 + 3], p * q,
                       fmaf(cf[240 + j*4 + 2], q,
                       fmaf(cf[240 + j*4 + 1], p, cf[240 + j*4 + 0])));
        }
    }
    // ---- Layer 3: 4 -> 2 ----
    float h3[SPT][2];
    #pragma unroll
    for (int j = 0; j < 2; ++j) {
        #pragma unroll
        for (int s = 0; s < SPT; ++s) {
            float p = 0.f, q = 0.f;
            #pragma unroll
            for (int i = 0; i < 4; ++i) {
                p = fmaf(h2[s][i], cf[256 + j * 4 + i], p);
                q = fmaf(h2[s][i], cf[264 + j * 4 + i], q);
            }
            h3[s][j] = fmaf(cf[272 + j*4 + 3], p * q,
                       fmaf(cf[272 + j*4 + 2], q,
                       fmaf(cf[272 + j*4 + 1], p, cf[272 + j*4 + 0])));
        }
    }
    // ---- Layer 4: 2 -> 1, one float4 store per thread ----
    float o[SPT];
    #pragma unroll
    for (int s = 0; s < SPT; ++s) {
        float p = fmaf(h3[s][0], cf[280], h3[s][1] * cf[281]);
        float q = fmaf(h3[s][0], cf[282], h3[s][1] * cf[283]);
        o[s] = fmaf(cf[287], p * q,
               fmaf(cf[286], q,
               fmaf(cf[285], p, cf[284])));
    }
    if (b0 + SPT <= nB) {
        float4* __restrict__ out4 = (float4*)out;
        float4 w; w.x = o[0]; w.y = o[1]; w.z = o[2]; w.w = o[3];
        out4[T] = w;
    } else {
        #pragma unroll
        for (int s = 0; s < SPT; ++s)
            if (b0 + s < nB) out[b0 + s] = o[s];
    }
}

extern "C" void kernel_launch(void* const* d_in, const int* in_sizes, int n_in,
                              void* d_out, int out_size, void* d_ws, size_t ws_size,
                              hipStream_t stream) {
    const float* x   = (const float*)d_in[0];
    const float* sa1 = (const float*)d_in[1];
    const float* sb1 = (const float*)d_in[2];
    const float* g1  = (const float*)d_in[3];
    const float* sa2 = (const float*)d_in[4];
    const float* sb2 = (const float*)d_in[5];
    const float* g2  = (const float*)d_in[6];
    const float* sa3 = (const float*)d_in[7];
    const float* sb3 = (const float*)d_in[8];
    const float* g3  = (const float*)d_in[9];
    const float* sa4 = (const float*)d_in[10];
    const float* sb4 = (const float*)d_in[11];
    const float* g4  = (const float*)d_in[12];
    float* cf = (float*)d_ws;                 // 288 floats of scratch
    const int nB = in_sizes[0] / 9;

    coeff_kernel<<<1, 64, 0, stream>>>(sa1, sb1, g1, sa2, sb2, g2,
                                       sa3, sb3, g3, sa4, sb4, g4, cf);
    const int grid = (nB + B_PER_BLOCK - 1) / B_PER_BLOCK;
    net_kernel<<<grid, THREADS, 0, stream>>>(x, cf, (float*)d_out, nB);
}